// Round 7
// baseline (206.554 us; speedup 1.0000x reference)
//
#include <hip/hip_runtime.h>
#include <hip/hip_bf16.h>
#include <stdint.h>
#include <stddef.h>

// ---------- types ----------
typedef __bf16 b16;
typedef __bf16 b16x4 __attribute__((ext_vector_type(4)));
typedef __bf16 b16x8 __attribute__((ext_vector_type(8)));
typedef float  f32x4 __attribute__((ext_vector_type(4)));

#define LOG2E 1.4426950408889634f
#define QSCALE (0.125f * LOG2E)   // 1/sqrt(64) folded with log2(e): softmax in exp2 domain

#if __has_builtin(__builtin_amdgcn_exp2f)
#define EXP2F(x) __builtin_amdgcn_exp2f(x)
#else
#define EXP2F(x) exp2f(x)
#endif

typedef __attribute__((address_space(1))) void gvoid;
typedef __attribute__((address_space(3))) void svoid;

// async global->LDS, 16B per lane. LDS dest must be wave-uniform base + lane*16.
__device__ __forceinline__ void async_cp16(void* lds, const void* g) {
    __builtin_amdgcn_global_load_lds((gvoid*)(void*)g, (svoid*)lds, 16, 0, 0);
}

// XOR swizzle on 16B chunk index (bank-group spread for the permuted-row reads)
#define SW(r) ((((r) & 7)) ^ (((r) >> 1) & 4))

// ---------- kernel 1: prep = x fp32->bf16 (z==4) + W transposes (z<4) ----------
__global__ __launch_bounds__(256) void k_prep(const float* __restrict__ x,
                                              const float* __restrict__ Wq,
                                              const float* __restrict__ Wk,
                                              const float* __restrict__ Wv,
                                              const float* __restrict__ Wo,
                                              b16* __restrict__ Xb,
                                              b16* __restrict__ WtQKV,
                                              b16* __restrict__ Wot) {
    const int z = blockIdx.z;
    if (z == 4) {
        // convert x: 1024 blocks * 4096 floats = 2*2048*1024 exactly
        const int blk = blockIdx.y * 32 + blockIdx.x;
        const float* src = x + (size_t)blk * 4096;
        b16* dst = Xb + (size_t)blk * 4096;
#pragma unroll
        for (int c = 0; c < 4; ++c) {
            const int i = c * 1024 + threadIdx.x * 4;
            float4 v = *(const float4*)(src + i);
            b16x4 o = { (b16)v.x, (b16)v.y, (b16)v.z, (b16)v.w };
            *(b16x4*)(dst + i) = o;
        }
        return;
    }
    __shared__ float t[32][33];
    const float* W = (z == 0) ? Wq : (z == 1) ? Wk : (z == 2) ? Wv : Wo;
    const int k0 = blockIdx.x * 32, n0 = blockIdx.y * 32;
    const int tr = threadIdx.x >> 3, tc4 = (threadIdx.x & 7) * 4;
    float4 v = *(const float4*)(W + (size_t)(k0 + tr) * 1024 + n0 + tc4);
    t[tr][tc4 + 0] = v.x; t[tr][tc4 + 1] = v.y;
    t[tr][tc4 + 2] = v.z; t[tr][tc4 + 3] = v.w;
    __syncthreads();
    b16* dst = (z < 3) ? (WtQKV + ((size_t)z << 20)) : Wot;
    b16x4 o = { (b16)t[tc4 + 0][tr], (b16)t[tc4 + 1][tr],
                (b16)t[tc4 + 2][tr], (b16)t[tc4 + 3][tr] };
    *(b16x4*)(dst + (size_t)(n0 + tr) * 1024 + k0 + tc4) = o;
}

// ---------- shared GEMM core: C[128x128] = A[128xK] * Bt[128xK]^T, K=1024 ----------
// RING-3 staging, BK=32: stage tile t+2 while computing tile t; counted
// vmcnt(8) (2 tiles in flight, never drained mid-loop). 48KB LDS -> 3
// blocks/CU. Barrier2 sits BEFORE the MFMAs (reg-only) so they overlap staging.
__device__ __forceinline__ void gemm128_core(const b16* __restrict__ Ag,
                                             const b16* __restrict__ Bg,
                                             b16* As, b16* Bs, int tid,
                                             f32x4 acc[4][4]) {
    const int lane = tid & 63, wave = tid >> 6;
    const int wm = wave & 1, wn = wave >> 1;
    const int quad = lane >> 4, lc = lane & 15;
    const int ci0 = tid, ci1 = tid + 256;
    const b16* a0 = Ag + (ci0 >> 2) * 1024 + (ci0 & 3) * 8;
    const b16* a1 = Ag + (ci1 >> 2) * 1024 + (ci1 & 3) * 8;
    const b16* b0 = Bg + (ci0 >> 2) * 1024 + (ci0 & 3) * 8;
    const b16* b1 = Bg + (ci1 >> 2) * 1024 + (ci1 & 3) * 8;

#define GSTAGE(BUF, K0) do {                                   \
        async_cp16(As + (BUF) * 4096 + ci0 * 8, a0 + (K0));    \
        async_cp16(As + (BUF) * 4096 + ci1 * 8, a1 + (K0));    \
        async_cp16(Bs + (BUF) * 4096 + ci0 * 8, b0 + (K0));    \
        async_cp16(Bs + (BUF) * 4096 + ci1 * 8, b1 + (K0));    \
    } while (0)

    // one K-step: optional stage of tile t+2, wait for tile t, read frags,
    // release buffer (barrier2), then MFMA on registers.
#define GSTEP(BUF, SBUF, SK0, VM, DOSTAGE) do {                          \
        if (DOSTAGE) GSTAGE(SBUF, SK0);                                  \
        asm volatile("s_waitcnt vmcnt(" #VM ")" ::: "memory");           \
        __builtin_amdgcn_s_barrier();                                    \
        __builtin_amdgcn_sched_barrier(0);                               \
        b16x8 af[4], bfr[4];                                             \
        const b16* Al = As + (BUF) * 4096;                               \
        const b16* Bl = Bs + (BUF) * 4096;                               \
        _Pragma("unroll")                                                \
        for (int mt = 0; mt < 4; ++mt)                                   \
            af[mt] = *(const b16x8*)(Al + (wm * 64 + mt * 16 + lc) * 32 + quad * 8); \
        _Pragma("unroll")                                                \
        for (int nt = 0; nt < 4; ++nt)                                   \
            bfr[nt] = *(const b16x8*)(Bl + (wn * 64 + nt * 16 + lc) * 32 + quad * 8); \
        asm volatile("s_waitcnt lgkmcnt(0)" ::: "memory");               \
        __builtin_amdgcn_sched_barrier(0);                               \
        __builtin_amdgcn_s_barrier();                                    \
        __builtin_amdgcn_s_setprio(1);                                   \
        _Pragma("unroll")                                                \
        for (int mt = 0; mt < 4; ++mt)                                   \
            _Pragma("unroll")                                            \
            for (int nt = 0; nt < 4; ++nt)                               \
                acc[mt][nt] = __builtin_amdgcn_mfma_f32_16x16x32_bf16(   \
                    af[mt], bfr[nt], acc[mt][nt], 0, 0, 0);              \
        __builtin_amdgcn_s_setprio(0);                                   \
    } while (0)

    // prologue: tiles 0,1 in flight
    GSTAGE(0, 0);
    GSTAGE(1, 32);
    // main: t = 0..29 in 10 x 3 phases (buf = t%3, stage t+2 -> (t+2)%3)
    for (int i = 0; i < 10; ++i) {
        const int kb = 96 * i;
        GSTEP(0, 2, kb + 64, 8, 1);
        GSTEP(1, 0, kb + 96, 8, 1);
        GSTEP(2, 1, kb + 128, 8, 1);
    }
    // tail: t=30 (buf0, tile31 still in flight), t=31 (buf1, drain)
    GSTEP(0, 0, 0, 4, 0);
    GSTEP(1, 0, 0, 0, 0);
#undef GSTEP
#undef GSTAGE
}

// ---------- kernel 2: fused QKV projection, LDS-bounce coalesced epilogue ----------
// After the K loop the ring LDS is dead -> overlay a 128x128 bf16 tile.
// Q/K stash as [s][n], V stash TRANSPOSED as [n][s]; both use a 16B-chunk
// XOR swizzle (chunk ^= row&15) so stash and readback are bank-clean. Readback:
// 8 lanes per 128B half-row -> every global_store_dwordx4 covers full lines.
__global__ __launch_bounds__(256, 3) void k_gemm_qkv(
    const b16* __restrict__ A, const b16* __restrict__ Bt,
    const float* __restrict__ bq, const float* __restrict__ bk,
    const float* __restrict__ bv,
    b16* __restrict__ Qg, b16* __restrict__ Kg, b16* __restrict__ Vtg) {
    __shared__ __align__(16) b16 LB[24576];   // As(12288) | Bs(12288); Tb overlay
    b16* As = LB;
    b16* Bs = LB + 12288;
    char* Tb = (char*)LB;                      // 128x128 bf16 tile = 32KB
    const int bm = blockIdx.x, bn = blockIdx.y;
    const int tid = threadIdx.x;
    const int lane = tid & 63, wave = tid >> 6;
    const int wm = wave & 1, wn = wave >> 1;
    const int quad = lane >> 4, lc = lane & 15;

    f32x4 acc[4][4] = {};
    gemm128_core(A + (size_t)(bm * 128) * 1024, Bt + (size_t)(bn * 128) * 1024,
                 As, Bs, tid, acc);
    // core's trailing s_barrier: all waves done with As/Bs -> Tb overlay safe

    const int mat = bn >> 3;
    const float* bp = (mat == 0) ? bq : (mat == 1) ? bk : bv;
    const float scl = (mat == 0) ? QSCALE : 1.0f;

#pragma unroll
    for (int nt = 0; nt < 4; ++nt) {
        const int ln = wn * 64 + nt * 16 + lc;           // local col n: 0..127
        const float bval = bp[(bn * 128 + ln) & 1023];
#pragma unroll
        for (int mt = 0; mt < 4; ++mt) {
            const int lm = wm * 64 + mt * 16 + quad * 4; // local row s base
            if (mat == 2) {
                // V: tile row = n, cols = s; pack 4 along s -> one 8B write
                b16x4 o;
#pragma unroll
                for (int r = 0; r < 4; ++r) o[r] = (b16)(acc[mt][nt][r] + bval);
                const int byte = ln * 256 + (((lm >> 3) ^ (ln & 15)) << 4) + (lm & 7) * 2;
                *(b16x4*)(Tb + byte) = o;
            } else {
                // Q/K: tile row = s, cols = n; scalar stash (quad spreads banks via XOR)
#pragma unroll
                for (int r = 0; r < 4; ++r) {
                    const int row = lm + r;
                    const int byte = row * 256 + (((ln >> 3) ^ (row & 15)) << 4) + (ln & 7) * 2;
                    *(b16*)(Tb + byte) = (b16)((acc[mt][nt][r] + bval) * scl);
                }
            }
        }
    }
    __syncthreads();

    // coalesced copy-out: 256 half-rows (128B each), 8 threads per half-row
    const int chunk = tid & 7, hr0 = tid >> 3;   // hr0: 0..31
    const int b = bm >> 4;                        // batch (128-row block within one batch)
    const int s_blk = (bm * 128) & 2047;
#pragma unroll
    for (int p = 0; p < 8; ++p) {
        const int hr = p * 32 + hr0;              // 0..255
        const int row = hr >> 1, half = hr & 1;
        const int c2 = (half * 8 + chunk) ^ (row & 15);
        b16x8 v = *(const b16x8*)(Tb + row * 256 + c2 * 16);
        if (mat == 2) {
            // row = local n, cols = s
            const int cm = (bn * 128 + row) & 1023;
            const int h = cm >> 6, dh = cm & 63;
            *(b16x8*)(Vtg + (size_t)((b * 16 + h) * 64 + dh) * 2048 +
                      s_blk + half * 64 + chunk * 8) = v;
        } else {
            // row = local s, cols = n (head boundary at local n=64)
            const int s = s_blk + row;
            const int cm = (bn * 128 + half * 64 + chunk * 8) & 1023;
            const int h = cm >> 6, dh = cm & 63;
            b16* dst = (mat == 0) ? Qg : Kg;
            *(b16x8*)(dst + ((size_t)(b * 16 + h) * 2048 + s) * 64 + dh) = v;
        }
    }
}

// ---------- kernel 3: flash attention, no-max exp2 softmax, 64 q/wave ----------
// Block: 128 q rows of one (b,h), 2 waves x 64 q rows. 512 blocks = 2/CU.
// Each wave owns 4 q-tiles (qt) -> every kf/vf ds_read_b128 feeds 4 MFMAs
// (was 1), cutting LDS-pipe demand 4x (R6 diagnosis: flash was LDS-bound,
// 16 reads x 12cyc x 16 waves/CU ~= the entire 47us runtime).
// In-register P via permuted K rows (krow = ks*32 + (lc>>2)*8 + t*4 + (lc&3)):
// S^T output leaves each lane holding exactly keys quad*8+{t*4+r} -> PV
// A-fragment assembled with zero cross-lane ops; P never touches LDS.
// Double-buffered K/V with counted vmcnt(8); never drained mid-loop.
__global__ __launch_bounds__(128, 2) void k_flash(
    const b16* __restrict__ Qg, const b16* __restrict__ Kg,
    const b16* __restrict__ Vtg, b16* __restrict__ AO) {
    __shared__ __align__(16) b16 Ks[2 * 64 * 64];   // double-buffered K tile
    __shared__ __align__(16) b16 Vs[2 * 64 * 64];   // double-buffered V^T tile
    __shared__ float Lred[2][64];                   // per-wave l exchange
    // LDS = 32.5 KiB -> 2 blocks/CU resident (512-block grid, one round)

    // bid = qb*32 + bh: same-bh blocks differ by 32 (0 mod 8) -> same XCD.
    const int bid = blockIdx.x;
    const int qb = bid >> 5;       // 0..15
    const int bh = bid & 31;

    const int tid = threadIdx.x, lane = tid & 63, wave = tid >> 6;  // wave 0..1
    const int quad = lane >> 4, lc = lane & 15;

    const b16* Kbh = Kg + (size_t)bh * 2048 * 64;
    const b16* Vbh = Vtg + (size_t)bh * 64 * 2048;

    // staging source pointers: 128 threads x 4 chunks each cover 512 x 16B
    // (8KB K + 8KB V); advance per tile; LDS dest stays linear.
    const b16* pK[4];
    const b16* pV[4];
    int ci[4];
#pragma unroll
    for (int j = 0; j < 4; ++j) {
        ci[j] = tid + j * 128;
        const int r = ci[j] >> 3, cs = ci[j] & 7;
        const int gc = cs ^ SW(r);
        pK[j] = Kbh + r * 64 + gc * 8;
        pV[j] = Vbh + (size_t)r * 2048 + gc * 8;
    }

#define FSTAGE(BUF) do {                                       \
        _Pragma("unroll")                                      \
        for (int j = 0; j < 4; ++j) {                          \
            async_cp16(Ks + (BUF) * 4096 + ci[j] * 8, pK[j]);  \
            async_cp16(Vs + (BUF) * 4096 + ci[j] * 8, pV[j]);  \
            pK[j] += 4096; pV[j] += 64;                        \
        }                                                      \
    } while (0)

    // prologue: stage tile 0 (latency hides under Q loads)
    FSTAGE(0);

    // Q fragments (B-operand: n=q=lc, k=d=quad*8+j), 64 q rows per wave
    const b16* Qbase = Qg + ((size_t)bh * 2048 + qb * 128 + wave * 64) * 64;
    b16x8 qf[4][2];
#pragma unroll
    for (int qt = 0; qt < 4; ++qt)
#pragma unroll
        for (int ch = 0; ch < 2; ++ch)
            qf[qt][ch] = *(const b16x8*)(Qbase + (qt * 16 + lc) * 64 + ch * 32 + quad * 8);

    f32x4 oacc[4][4] = {};
    float lsum[4] = {0.f, 0.f, 0.f, 0.f};

    auto flash_tile = [&](const b16* Kc, const b16* Vc) {
#pragma unroll
        for (int ks = 0; ks < 2; ++ks) {
            b16x8 pf[4];
#pragma unroll
            for (int t = 0; t < 2; ++t) {
                const int krow = ks * 32 + (lc >> 2) * 8 + t * 4 + (lc & 3);
                b16x8 kf0 = *(const b16x8*)(Kc + krow * 64 + ((0 * 4 + quad) ^ SW(krow)) * 8);
                b16x8 kf1 = *(const b16x8*)(Kc + krow * 64 + ((1 * 4 + quad) ^ SW(krow)) * 8);
#pragma unroll
                for (int qt = 0; qt < 4; ++qt) {
                    f32x4 s = {};
                    s = __builtin_amdgcn_mfma_f32_16x16x32_bf16(kf0, qf[qt][0], s, 0, 0, 0);
                    s = __builtin_amdgcn_mfma_f32_16x16x32_bf16(kf1, qf[qt][1], s, 0, 0, 0);
                    // lane holds S[key = ks*32 + quad*8 + t*4 + r][q = qt*16+lc]
                    float e0 = EXP2F(s[0]), e1 = EXP2F(s[1]);
                    float e2 = EXP2F(s[2]), e3 = EXP2F(s[3]);
                    lsum[qt] += (e0 + e1) + (e2 + e3);
                    pf[qt][t * 4 + 0] = (b16)e0;
                    pf[qt][t * 4 + 1] = (b16)e1;
                    pf[qt][t * 4 + 2] = (b16)e2;
                    pf[qt][t * 4 + 3] = (b16)e3;
                }
            }
            b16x8 vf[4];
#pragma unroll
            for (int dt = 0; dt < 4; ++dt) {
                const int row = dt * 16 + lc;
                vf[dt] = *(const b16x8*)(Vc + row * 64 + ((ks * 4 + quad) ^ SW(row)) * 8);
            }
            __builtin_amdgcn_s_setprio(1);
#pragma unroll
            for (int qt = 0; qt < 4; ++qt)
#pragma unroll
                for (int dt = 0; dt < 4; ++dt)
                    oacc[qt][dt] = __builtin_amdgcn_mfma_f32_16x16x32_bf16(
                        pf[qt], vf[dt], oacc[qt][dt], 0, 0, 0);
            __builtin_amdgcn_s_setprio(0);
        }
    };

    for (int kt = 0; kt < 32; kt += 2) {
        // half 0: stage buf1 (tile kt+1), compute buf0 (tile kt)
        FSTAGE(1);
        asm volatile("s_waitcnt vmcnt(8)" ::: "memory");
        __builtin_amdgcn_s_barrier();
        __builtin_amdgcn_sched_barrier(0);
        flash_tile(Ks, Vs);
        __builtin_amdgcn_sched_barrier(0);
        __builtin_amdgcn_s_barrier();
        // half 1: stage buf0 (tile kt+2) unless done, compute buf1 (tile kt+1)
        if (kt + 2 < 32) {
            FSTAGE(0);
            asm volatile("s_waitcnt vmcnt(8)" ::: "memory");
        } else {
            asm volatile("s_waitcnt vmcnt(0)" ::: "memory");
        }
        __builtin_amdgcn_s_barrier();
        __builtin_amdgcn_sched_barrier(0);
        flash_tile(Ks + 4096, Vs + 4096);
        __builtin_amdgcn_sched_barrier(0);
        __builtin_amdgcn_s_barrier();
    }
#undef FSTAGE

    // reduce l across quads (lane holds partial l for q=qt*16+lc)
#pragma unroll
    for (int qt = 0; qt < 4; ++qt) {
        lsum[qt] += __shfl_xor(lsum[qt], 16, 64);
        lsum[qt] += __shfl_xor(lsum[qt], 32, 64);
    }

    // redistribute l via per-wave LDS, write AO directly
    if (quad == 0) {
#pragma unroll
        for (int qt = 0; qt < 4; ++qt) Lred[wave][qt * 16 + lc] = lsum[qt];
    }
    const int b = bh >> 4, h = bh & 15;
#pragma unroll
    for (int qt = 0; qt < 4; ++qt)
#pragma unroll
        for (int r = 0; r < 4; ++r) {
            const float inv = 1.0f / Lred[wave][qt * 16 + quad * 4 + r];
            const int s = qb * 128 + wave * 64 + qt * 16 + quad * 4 + r;
#pragma unroll
            for (int dt = 0; dt < 4; ++dt)
                AO[(size_t)(b * 2048 + s) * 1024 + h * 64 + dt * 16 + lc] =
                    (b16)(oacc[qt][dt][r] * inv);
        }
}

// ---------- kernel 4: output projection, fp32 epilogue ----------
__global__ __launch_bounds__(256, 3) void k_gemm_out(
    const b16* __restrict__ A, const b16* __restrict__ Bt,
    const float* __restrict__ bo, float* __restrict__ out) {
    __shared__ __align__(16) b16 As[3 * 128 * 32];
    __shared__ __align__(16) b16 Bs[3 * 128 * 32];
    const int bm = blockIdx.x, bn = blockIdx.y;
    const int tid = threadIdx.x;
    const int lane = tid & 63, wave = tid >> 6;
    const int wm = wave & 1, wn = wave >> 1;
    const int quad = lane >> 4, lc = lane & 15;

    f32x4 acc[4][4] = {};
    gemm128_core(A + (size_t)(bm * 128) * 1024, Bt + (size_t)(bn * 128) * 1024,
                 As, Bs, tid, acc);

#pragma unroll
    for (int nt = 0; nt < 4; ++nt) {
        const int n = bn * 128 + wn * 64 + nt * 16 + lc;
        const float bval = bo[n];
#pragma unroll
        for (int mt = 0; mt < 4; ++mt) {
            const int m0 = bm * 128 + wm * 64 + mt * 16 + quad * 4;
#pragma unroll
            for (int r = 0; r < 4; ++r)
                out[(size_t)(m0 + r) * 1024 + n] = acc[mt][nt][r] + bval;
        }
    }
}

// ---------- launcher ----------
extern "C" void kernel_launch(void* const* d_in, const int* in_sizes, int n_in,
                              void* d_out, int out_size, void* d_ws, size_t ws_size,
                              hipStream_t stream) {
    const float* x  = (const float*)d_in[0];
    const float* Wq = (const float*)d_in[1];
    const float* bq = (const float*)d_in[2];
    const float* Wk = (const float*)d_in[3];
    const float* bk = (const float*)d_in[4];
    const float* Wv = (const float*)d_in[5];
    const float* bv = (const float*)d_in[6];
    const float* Wo = (const float*)d_in[7];
    const float* bo = (const float*)d_in[8];
    float* out = (float*)d_out;

    char* ws = (char*)d_ws;
    const size_t MB = 1024 * 1024;
    b16* Xb  = (b16*)(ws);             // [4096][1024] bf16 (dead after qkv)
    b16* AO  = (b16*)(ws);             // [4096][1024] bf16 (overlay on Xb)
    b16* WtQ = (b16*)(ws + 8 * MB);    // [3072][1024] bf16
    b16* Wot = (b16*)(ws + 14 * MB);   // [1024][1024] bf16
    b16* Qg  = (b16*)(ws + 16 * MB);   // [32][2048][64] bf16 (pre-scaled)
    b16* Kg  = (b16*)(ws + 24 * MB);   // [32][2048][64] bf16
    b16* Vtg = (b16*)(ws + 32 * MB);   // [32][64][2048] bf16

    k_prep<<<dim3(32, 32, 5), 256, 0, stream>>>(x, Wq, Wk, Wv, Wo, Xb, WtQ, Wot);
    k_gemm_qkv<<<dim3(32, 24), 256, 0, stream>>>(Xb, WtQ, bq, bk, bv, Qg, Kg, Vtg);
    k_flash<<<dim3(512), 128, 0, stream>>>(Qg, Kg, Vtg, AO);
    k_gemm_out<<<dim3(32, 8), 256, 0, stream>>>(AO, Wot, bo, out);
}

// Round 8
// 189.301 us; speedup vs baseline: 1.0911x; 1.0911x over previous
//
#include <hip/hip_runtime.h>
#include <hip/hip_bf16.h>
#include <stdint.h>
#include <stddef.h>

// ---------- types ----------
typedef __bf16 b16;
typedef __bf16 b16x4 __attribute__((ext_vector_type(4)));
typedef __bf16 b16x8 __attribute__((ext_vector_type(8)));
typedef float  f32x4 __attribute__((ext_vector_type(4)));

#define LOG2E 1.4426950408889634f
#define QSCALE (0.125f * LOG2E)   // 1/sqrt(64) folded with log2(e): softmax in exp2 domain

#if __has_builtin(__builtin_amdgcn_exp2f)
#define EXP2F(x) __builtin_amdgcn_exp2f(x)
#else
#define EXP2F(x) exp2f(x)
#endif

typedef __attribute__((address_space(1))) void gvoid;
typedef __attribute__((address_space(3))) void svoid;

// async global->LDS, 16B per lane. LDS dest must be wave-uniform base + lane*16.
__device__ __forceinline__ void async_cp16(void* lds, const void* g) {
    __builtin_amdgcn_global_load_lds((gvoid*)(void*)g, (svoid*)lds, 16, 0, 0);
}

// XOR swizzle on 16B chunk index (bank-group spread for the permuted-row reads)
#define SW(r) ((((r) & 7)) ^ (((r) >> 1) & 4))

// ---------- kernel 1: prep = x fp32->bf16 (z==4) + W transposes (z<4) ----------
__global__ __launch_bounds__(256) void k_prep(const float* __restrict__ x,
                                              const float* __restrict__ Wq,
                                              const float* __restrict__ Wk,
                                              const float* __restrict__ Wv,
                                              const float* __restrict__ Wo,
                                              b16* __restrict__ Xb,
                                              b16* __restrict__ WtQKV,
                                              b16* __restrict__ Wot) {
    const int z = blockIdx.z;
    if (z == 4) {
        // convert x: 1024 blocks * 4096 floats = 2*2048*1024 exactly
        const int blk = blockIdx.y * 32 + blockIdx.x;
        const float* src = x + (size_t)blk * 4096;
        b16* dst = Xb + (size_t)blk * 4096;
#pragma unroll
        for (int c = 0; c < 4; ++c) {
            const int i = c * 1024 + threadIdx.x * 4;
            float4 v = *(const float4*)(src + i);
            b16x4 o = { (b16)v.x, (b16)v.y, (b16)v.z, (b16)v.w };
            *(b16x4*)(dst + i) = o;
        }
        return;
    }
    __shared__ float t[32][33];
    const float* W = (z == 0) ? Wq : (z == 1) ? Wk : (z == 2) ? Wv : Wo;
    const int k0 = blockIdx.x * 32, n0 = blockIdx.y * 32;
    const int tr = threadIdx.x >> 3, tc4 = (threadIdx.x & 7) * 4;
    float4 v = *(const float4*)(W + (size_t)(k0 + tr) * 1024 + n0 + tc4);
    t[tr][tc4 + 0] = v.x; t[tr][tc4 + 1] = v.y;
    t[tr][tc4 + 2] = v.z; t[tr][tc4 + 3] = v.w;
    __syncthreads();
    b16* dst = (z < 3) ? (WtQKV + ((size_t)z << 20)) : Wot;
    b16x4 o = { (b16)t[tc4 + 0][tr], (b16)t[tc4 + 1][tr],
                (b16)t[tc4 + 2][tr], (b16)t[tc4 + 3][tr] };
    *(b16x4*)(dst + (size_t)(n0 + tr) * 1024 + k0 + tc4) = o;
}

// ---------- shared GEMM core: C[128x128] = A[128xK] * Bt[128xK]^T, K=1024 ----------
// RING-3 staging, BK=32: stage tile t+2 while computing tile t; counted
// vmcnt(8) (2 tiles in flight, never drained mid-loop). 48KB LDS -> 3
// blocks/CU. Barrier2 sits BEFORE the MFMAs (reg-only) so they overlap staging.
__device__ __forceinline__ void gemm128_core(const b16* __restrict__ Ag,
                                             const b16* __restrict__ Bg,
                                             b16* As, b16* Bs, int tid,
                                             f32x4 acc[4][4]) {
    const int lane = tid & 63, wave = tid >> 6;
    const int wm = wave & 1, wn = wave >> 1;
    const int quad = lane >> 4, lc = lane & 15;
    const int ci0 = tid, ci1 = tid + 256;
    const b16* a0 = Ag + (ci0 >> 2) * 1024 + (ci0 & 3) * 8;
    const b16* a1 = Ag + (ci1 >> 2) * 1024 + (ci1 & 3) * 8;
    const b16* b0 = Bg + (ci0 >> 2) * 1024 + (ci0 & 3) * 8;
    const b16* b1 = Bg + (ci1 >> 2) * 1024 + (ci1 & 3) * 8;

#define GSTAGE(BUF, K0) do {                                   \
        async_cp16(As + (BUF) * 4096 + ci0 * 8, a0 + (K0));    \
        async_cp16(As + (BUF) * 4096 + ci1 * 8, a1 + (K0));    \
        async_cp16(Bs + (BUF) * 4096 + ci0 * 8, b0 + (K0));    \
        async_cp16(Bs + (BUF) * 4096 + ci1 * 8, b1 + (K0));    \
    } while (0)

    // one K-step: optional stage of tile t+2, wait for tile t, read frags,
    // release buffer (barrier2), then MFMA on registers.
#define GSTEP(BUF, SBUF, SK0, VM, DOSTAGE) do {                          \
        if (DOSTAGE) GSTAGE(SBUF, SK0);                                  \
        asm volatile("s_waitcnt vmcnt(" #VM ")" ::: "memory");           \
        __builtin_amdgcn_s_barrier();                                    \
        __builtin_amdgcn_sched_barrier(0);                               \
        b16x8 af[4], bfr[4];                                             \
        const b16* Al = As + (BUF) * 4096;                               \
        const b16* Bl = Bs + (BUF) * 4096;                               \
        _Pragma("unroll")                                                \
        for (int mt = 0; mt < 4; ++mt)                                   \
            af[mt] = *(const b16x8*)(Al + (wm * 64 + mt * 16 + lc) * 32 + quad * 8); \
        _Pragma("unroll")                                                \
        for (int nt = 0; nt < 4; ++nt)                                   \
            bfr[nt] = *(const b16x8*)(Bl + (wn * 64 + nt * 16 + lc) * 32 + quad * 8); \
        asm volatile("s_waitcnt lgkmcnt(0)" ::: "memory");               \
        __builtin_amdgcn_sched_barrier(0);                               \
        __builtin_amdgcn_s_barrier();                                    \
        __builtin_amdgcn_s_setprio(1);                                   \
        _Pragma("unroll")                                                \
        for (int mt = 0; mt < 4; ++mt)                                   \
            _Pragma("unroll")                                            \
            for (int nt = 0; nt < 4; ++nt)                               \
                acc[mt][nt] = __builtin_amdgcn_mfma_f32_16x16x32_bf16(   \
                    af[mt], bfr[nt], acc[mt][nt], 0, 0, 0);              \
        __builtin_amdgcn_s_setprio(0);                                   \
    } while (0)

    // prologue: tiles 0,1 in flight
    GSTAGE(0, 0);
    GSTAGE(1, 32);
    // main: t = 0..29 in 10 x 3 phases (buf = t%3, stage t+2 -> (t+2)%3)
    for (int i = 0; i < 10; ++i) {
        const int kb = 96 * i;
        GSTEP(0, 2, kb + 64, 8, 1);
        GSTEP(1, 0, kb + 96, 8, 1);
        GSTEP(2, 1, kb + 128, 8, 1);
    }
    // tail: t=30 (buf0, tile31 still in flight), t=31 (buf1, drain)
    GSTEP(0, 0, 0, 4, 0);
    GSTEP(1, 0, 0, 0, 0);
#undef GSTEP
#undef GSTAGE
}

// ---------- kernel 2: fused QKV projection, LDS-bounce coalesced epilogue ----------
// After the K loop the ring LDS is dead -> overlay a 128x128 bf16 tile.
// Q/K stash as [s][n], V stash TRANSPOSED as [n][s]; both use a 16B-chunk
// XOR swizzle (chunk ^= row&15) so stash and readback are bank-clean. Readback:
// 8 lanes per 128B half-row -> every global_store_dwordx4 covers full lines.
__global__ __launch_bounds__(256, 3) void k_gemm_qkv(
    const b16* __restrict__ A, const b16* __restrict__ Bt,
    const float* __restrict__ bq, const float* __restrict__ bk,
    const float* __restrict__ bv,
    b16* __restrict__ Qg, b16* __restrict__ Kg, b16* __restrict__ Vtg) {
    __shared__ __align__(16) b16 LB[24576];   // As(12288) | Bs(12288); Tb overlay
    b16* As = LB;
    b16* Bs = LB + 12288;
    char* Tb = (char*)LB;                      // 128x128 bf16 tile = 32KB
    const int bm = blockIdx.x, bn = blockIdx.y;
    const int tid = threadIdx.x;
    const int lane = tid & 63, wave = tid >> 6;
    const int wm = wave & 1, wn = wave >> 1;
    const int quad = lane >> 4, lc = lane & 15;

    f32x4 acc[4][4] = {};
    gemm128_core(A + (size_t)(bm * 128) * 1024, Bt + (size_t)(bn * 128) * 1024,
                 As, Bs, tid, acc);
    // core's trailing s_barrier: all waves done with As/Bs -> Tb overlay safe

    const int mat = bn >> 3;
    const float* bp = (mat == 0) ? bq : (mat == 1) ? bk : bv;
    const float scl = (mat == 0) ? QSCALE : 1.0f;

#pragma unroll
    for (int nt = 0; nt < 4; ++nt) {
        const int ln = wn * 64 + nt * 16 + lc;           // local col n: 0..127
        const float bval = bp[(bn * 128 + ln) & 1023];
#pragma unroll
        for (int mt = 0; mt < 4; ++mt) {
            const int lm = wm * 64 + mt * 16 + quad * 4; // local row s base
            if (mat == 2) {
                // V: tile row = n, cols = s; pack 4 along s -> one 8B write
                b16x4 o;
#pragma unroll
                for (int r = 0; r < 4; ++r) o[r] = (b16)(acc[mt][nt][r] + bval);
                const int byte = ln * 256 + (((lm >> 3) ^ (ln & 15)) << 4) + (lm & 7) * 2;
                *(b16x4*)(Tb + byte) = o;
            } else {
                // Q/K: tile row = s, cols = n; scalar stash (quad spreads banks via XOR)
#pragma unroll
                for (int r = 0; r < 4; ++r) {
                    const int row = lm + r;
                    const int byte = row * 256 + (((ln >> 3) ^ (row & 15)) << 4) + (ln & 7) * 2;
                    *(b16*)(Tb + byte) = (b16)((acc[mt][nt][r] + bval) * scl);
                }
            }
        }
    }
    __syncthreads();

    // coalesced copy-out: 256 half-rows (128B each), 8 threads per half-row
    const int chunk = tid & 7, hr0 = tid >> 3;   // hr0: 0..31
    const int b = bm >> 4;                        // batch (128-row block within one batch)
    const int s_blk = (bm * 128) & 2047;
#pragma unroll
    for (int p = 0; p < 8; ++p) {
        const int hr = p * 32 + hr0;              // 0..255
        const int row = hr >> 1, half = hr & 1;
        const int c2 = (half * 8 + chunk) ^ (row & 15);
        b16x8 v = *(const b16x8*)(Tb + row * 256 + c2 * 16);
        if (mat == 2) {
            // row = local n, cols = s
            const int cm = (bn * 128 + row) & 1023;
            const int h = cm >> 6, dh = cm & 63;
            *(b16x8*)(Vtg + (size_t)((b * 16 + h) * 64 + dh) * 2048 +
                      s_blk + half * 64 + chunk * 8) = v;
        } else {
            // row = local s, cols = n (head boundary at local n=64)
            const int s = s_blk + row;
            const int cm = (bn * 128 + half * 64 + chunk * 8) & 1023;
            const int h = cm >> 6, dh = cm & 63;
            b16* dst = (mat == 0) ? Qg : Kg;
            *(b16x8*)(dst + ((size_t)(b * 16 + h) * 2048 + s) * 64 + dh) = v;
        }
    }
}

// ---------- kernel 3: flash attention, 64 q/wave + np=2 key split ----------
// R7 lesson: 64 q/wave minimizes LDS traffic (4 MFMA per ds_read_b128) but
// caps total waves at 1024 = 1 wave/SIMD -> latency-bound (66us). Key-split
// (np) multiplies waves WITHOUT adding LDS traffic (each wave reads KV/np):
// np=2 -> 2048 waves = 2/SIMD. Partial O (fp32) + l merged by k_merge.
// Block: 256 q rows of one (b,h), 4 waves x 64 q, 16 key tiles per part.
// In-register P via permuted K rows; double-buffered K/V, counted vmcnt(4).
__global__ __launch_bounds__(256, 2) void k_flash(
    const b16* __restrict__ Qg, const b16* __restrict__ Kg,
    const b16* __restrict__ Vtg,
    float* __restrict__ Opart, float* __restrict__ lpart,
    b16* __restrict__ AO, int ktiles, int direct, int np) {
    __shared__ __align__(16) b16 Ks[2 * 64 * 64];   // double-buffered K tile
    __shared__ __align__(16) b16 Vs[2 * 64 * 64];   // double-buffered V^T tile
    __shared__ float Lred[4][64];                   // per-wave l exchange
    // LDS = 33 KiB -> 2 blocks/CU resident (512-block grid at np=2)

    // bid = qb*(32*np) + bh*np + part: same-(bh,part) blocks differ by 32*np
    // (0 mod 8) -> same XCD under round-robin dispatch.
    const int bid = blockIdx.x;
    const int gstride = np << 5;
    const int qb = bid / gstride;               // 0..7
    const int rem = bid - qb * gstride;
    const int bh = rem / np;
    const int part = rem - bh * np;

    const int tid = threadIdx.x, lane = tid & 63, wave = tid >> 6;
    const int quad = lane >> 4, lc = lane & 15;

    const b16* Kbh = Kg + (size_t)bh * 2048 * 64;
    const b16* Vbh = Vtg + (size_t)bh * 64 * 2048;
    const int kt0 = part * ktiles;

    // staging source pointers (advance per tile; LDS dest stays linear)
    const int ci0 = tid, ci1 = tid + 256;
    const int r0 = ci0 >> 3, gc0 = (ci0 & 7) ^ SW(r0);
    const int r1 = ci1 >> 3, gc1 = (ci1 & 7) ^ SW(r1);
    const b16* pK0 = Kbh + (size_t)(kt0 * 64 + r0) * 64 + gc0 * 8;
    const b16* pK1 = Kbh + (size_t)(kt0 * 64 + r1) * 64 + gc1 * 8;
    const b16* pV0 = Vbh + (size_t)r0 * 2048 + kt0 * 64 + gc0 * 8;
    const b16* pV1 = Vbh + (size_t)r1 * 2048 + kt0 * 64 + gc1 * 8;

#define FSTAGE(BUF) do {                                   \
        async_cp16(Ks + (BUF) * 4096 + ci0 * 8, pK0);      \
        async_cp16(Ks + (BUF) * 4096 + ci1 * 8, pK1);      \
        async_cp16(Vs + (BUF) * 4096 + ci0 * 8, pV0);      \
        async_cp16(Vs + (BUF) * 4096 + ci1 * 8, pV1);      \
        pK0 += 4096; pK1 += 4096; pV0 += 64; pV1 += 64;    \
    } while (0)

    // prologue: stage tile kt0 (latency hides under Q loads)
    FSTAGE(0);

    // Q fragments (B-operand: n=q=lc, k=d=quad*8+j), 64 q rows per wave
    const b16* Qbase = Qg + ((size_t)bh * 2048 + qb * 256 + wave * 64) * 64;
    b16x8 qf[4][2];
#pragma unroll
    for (int qt = 0; qt < 4; ++qt)
#pragma unroll
        for (int ch = 0; ch < 2; ++ch)
            qf[qt][ch] = *(const b16x8*)(Qbase + (qt * 16 + lc) * 64 + ch * 32 + quad * 8);

    f32x4 oacc[4][4] = {};
    float lsum[4] = {0.f, 0.f, 0.f, 0.f};

    auto flash_tile = [&](const b16* Kc, const b16* Vc) {
#pragma unroll
        for (int ks = 0; ks < 2; ++ks) {
            b16x8 pf[4];
#pragma unroll
            for (int t = 0; t < 2; ++t) {
                const int krow = ks * 32 + (lc >> 2) * 8 + t * 4 + (lc & 3);
                b16x8 kf0 = *(const b16x8*)(Kc + krow * 64 + ((0 * 4 + quad) ^ SW(krow)) * 8);
                b16x8 kf1 = *(const b16x8*)(Kc + krow * 64 + ((1 * 4 + quad) ^ SW(krow)) * 8);
#pragma unroll
                for (int qt = 0; qt < 4; ++qt) {
                    f32x4 s = {};
                    s = __builtin_amdgcn_mfma_f32_16x16x32_bf16(kf0, qf[qt][0], s, 0, 0, 0);
                    s = __builtin_amdgcn_mfma_f32_16x16x32_bf16(kf1, qf[qt][1], s, 0, 0, 0);
                    // lane holds S[key = ks*32 + quad*8 + t*4 + r][q = qt*16+lc]
                    float e0 = EXP2F(s[0]), e1 = EXP2F(s[1]);
                    float e2 = EXP2F(s[2]), e3 = EXP2F(s[3]);
                    lsum[qt] += (e0 + e1) + (e2 + e3);
                    pf[qt][t * 4 + 0] = (b16)e0;
                    pf[qt][t * 4 + 1] = (b16)e1;
                    pf[qt][t * 4 + 2] = (b16)e2;
                    pf[qt][t * 4 + 3] = (b16)e3;
                }
            }
            b16x8 vf[4];
#pragma unroll
            for (int dt = 0; dt < 4; ++dt) {
                const int row = dt * 16 + lc;
                vf[dt] = *(const b16x8*)(Vc + row * 64 + ((ks * 4 + quad) ^ SW(row)) * 8);
            }
            __builtin_amdgcn_s_setprio(1);
#pragma unroll
            for (int qt = 0; qt < 4; ++qt)
#pragma unroll
                for (int dt = 0; dt < 4; ++dt)
                    oacc[qt][dt] = __builtin_amdgcn_mfma_f32_16x16x32_bf16(
                        pf[qt], vf[dt], oacc[qt][dt], 0, 0, 0);
            __builtin_amdgcn_s_setprio(0);
        }
    };

    for (int kt = 0; kt < ktiles; kt += 2) {
        // half 0: stage buf1 (tile kt+1), compute buf0 (tile kt)
        FSTAGE(1);
        asm volatile("s_waitcnt vmcnt(4)" ::: "memory");
        __builtin_amdgcn_s_barrier();
        __builtin_amdgcn_sched_barrier(0);
        flash_tile(Ks, Vs);
        __builtin_amdgcn_sched_barrier(0);
        __builtin_amdgcn_s_barrier();
        // half 1: stage buf0 (tile kt+2) unless done, compute buf1 (tile kt+1)
        if (kt + 2 < ktiles) {
            FSTAGE(0);
            asm volatile("s_waitcnt vmcnt(4)" ::: "memory");
        } else {
            asm volatile("s_waitcnt vmcnt(0)" ::: "memory");
        }
        __builtin_amdgcn_s_barrier();
        __builtin_amdgcn_sched_barrier(0);
        flash_tile(Ks + 4096, Vs + 4096);
        __builtin_amdgcn_sched_barrier(0);
        __builtin_amdgcn_s_barrier();
    }
#undef FSTAGE

    // reduce l across quads (lane holds partial l for q=qt*16+lc)
#pragma unroll
    for (int qt = 0; qt < 4; ++qt) {
        lsum[qt] += __shfl_xor(lsum[qt], 16, 64);
        lsum[qt] += __shfl_xor(lsum[qt], 32, 64);
    }

    if (!direct) {
        float* Op = Opart + ((size_t)(part * 32 + bh) * 2048 + qb * 256 + wave * 64) * 64;
#pragma unroll
        for (int qt = 0; qt < 4; ++qt)
#pragma unroll
            for (int dt = 0; dt < 4; ++dt)
#pragma unroll
                for (int r = 0; r < 4; ++r)
                    Op[(qt * 16 + quad * 4 + r) * 64 + dt * 16 + lc] = oacc[qt][dt][r];
        if (quad == 0) {
            float* lp = lpart + (size_t)(part * 32 + bh) * 2048 + qb * 256 + wave * 64;
#pragma unroll
            for (int qt = 0; qt < 4; ++qt) lp[qt * 16 + lc] = lsum[qt];
        }
    } else {
        // single-part fallback: redistribute l via per-wave LDS, write AO directly
        if (quad == 0) {
#pragma unroll
            for (int qt = 0; qt < 4; ++qt) Lred[wave][qt * 16 + lc] = lsum[qt];
        }
        const int b = bh >> 4, h = bh & 15;
#pragma unroll
        for (int qt = 0; qt < 4; ++qt)
#pragma unroll
            for (int r = 0; r < 4; ++r) {
                const float inv = 1.0f / Lred[wave][qt * 16 + quad * 4 + r];
                const int s = qb * 256 + wave * 64 + qt * 16 + quad * 4 + r;
#pragma unroll
                for (int dt = 0; dt < 4; ++dt)
                    AO[(size_t)(b * 2048 + s) * 1024 + h * 64 + dt * 16 + lc] =
                        (b16)(oacc[qt][dt][r] * inv);
            }
    }
}

// ---------- kernel 3b: merge partials: AO = (O0+O1)/(l0+l1) ----------
__global__ __launch_bounds__(256) void k_merge(const float* __restrict__ Opart,
                                               const float* __restrict__ lpart,
                                               b16* __restrict__ AO, int np) {
    const int bh = blockIdx.y;
    const int q = blockIdx.x * 16 + (threadIdx.x >> 4);
    const int d4 = (threadIdx.x & 15) * 4;
    const size_t qi = (size_t)bh * 2048 + q;
    f32x4 o = *(const f32x4*)(Opart + qi * 64 + d4);
    float l = lpart[qi];
    if (np == 2) {
        o += *(const f32x4*)(Opart + (qi + (size_t)32 * 2048) * 64 + d4);
        l += lpart[qi + (size_t)32 * 2048];
    }
    const float inv = 1.0f / l;
    const int b = bh >> 4, h = bh & 15;
    b16x4 ob = { (b16)(o[0] * inv), (b16)(o[1] * inv),
                 (b16)(o[2] * inv), (b16)(o[3] * inv) };
    *(b16x4*)(AO + (size_t)(b * 2048 + q) * 1024 + h * 64 + d4) = ob;
}

// ---------- kernel 4: output projection, fp32 epilogue ----------
__global__ __launch_bounds__(256, 3) void k_gemm_out(
    const b16* __restrict__ A, const b16* __restrict__ Bt,
    const float* __restrict__ bo, float* __restrict__ out) {
    __shared__ __align__(16) b16 As[3 * 128 * 32];
    __shared__ __align__(16) b16 Bs[3 * 128 * 32];
    const int bm = blockIdx.x, bn = blockIdx.y;
    const int tid = threadIdx.x;
    const int lane = tid & 63, wave = tid >> 6;
    const int wm = wave & 1, wn = wave >> 1;
    const int quad = lane >> 4, lc = lane & 15;

    f32x4 acc[4][4] = {};
    gemm128_core(A + (size_t)(bm * 128) * 1024, Bt + (size_t)(bn * 128) * 1024,
                 As, Bs, tid, acc);

#pragma unroll
    for (int nt = 0; nt < 4; ++nt) {
        const int n = bn * 128 + wn * 64 + nt * 16 + lc;
        const float bval = bo[n];
#pragma unroll
        for (int mt = 0; mt < 4; ++mt) {
            const int m0 = bm * 128 + wm * 64 + mt * 16 + quad * 4;
#pragma unroll
            for (int r = 0; r < 4; ++r)
                out[(size_t)(m0 + r) * 1024 + n] = acc[mt][nt][r] + bval;
        }
    }
}

// ---------- launcher ----------
extern "C" void kernel_launch(void* const* d_in, const int* in_sizes, int n_in,
                              void* d_out, int out_size, void* d_ws, size_t ws_size,
                              hipStream_t stream) {
    const float* x  = (const float*)d_in[0];
    const float* Wq = (const float*)d_in[1];
    const float* bq = (const float*)d_in[2];
    const float* Wk = (const float*)d_in[3];
    const float* bk = (const float*)d_in[4];
    const float* Wv = (const float*)d_in[5];
    const float* bv = (const float*)d_in[6];
    const float* Wo = (const float*)d_in[7];
    const float* bo = (const float*)d_in[8];
    float* out = (float*)d_out;

    char* ws = (char*)d_ws;
    const size_t MB = 1024 * 1024;
    b16* Xb  = (b16*)(ws);             // [4096][1024] bf16 (dead after qkv)
    b16* AO  = (b16*)(ws);             // [4096][1024] bf16 (overlay on Xb)
    b16* WtQ = (b16*)(ws + 8 * MB);    // [3072][1024] bf16
    b16* Wot = (b16*)(ws + 14 * MB);   // [1024][1024] bf16
    b16* Qg  = (b16*)(ws + 16 * MB);   // [32][2048][64] bf16 (pre-scaled)
    b16* Kg  = (b16*)(ws + 24 * MB);   // [32][2048][64] bf16
    b16* Vtg = (b16*)(ws + 32 * MB);   // [32][64][2048] bf16

    // attention partials (np=2 key-split if workspace allows)
    const size_t need2 = 40 * MB + 2 * (16 * MB) + 2 * 256 * 1024;
    const int np = (ws_size >= need2) ? 2 : 1;
    float* Opart = (float*)(ws + 40 * MB);                        // [np][32][2048][64] f32
    float* lpart = (float*)(ws + 40 * MB + (size_t)np * 16 * MB); // [np][32][2048] f32
    const int direct = (np == 1);

    k_prep<<<dim3(32, 32, 5), 256, 0, stream>>>(x, Wq, Wk, Wv, Wo, Xb, WtQ, Wot);
    k_gemm_qkv<<<dim3(32, 24), 256, 0, stream>>>(Xb, WtQ, bq, bk, bv, Qg, Kg, Vtg);
    k_flash<<<dim3(8 * 32 * np), 256, 0, stream>>>(Qg, Kg, Vtg, Opart, lpart, AO,
                                                   32 / np, direct, np);
    if (!direct)
        k_merge<<<dim3(128, 32), 256, 0, stream>>>(Opart, lpart, AO, np);
    k_gemm_out<<<dim3(32, 8), 256, 0, stream>>>(AO, Wot, bo, out);
}